// Round 4
// baseline (605.072 us; speedup 1.0000x reference)
//
#include <hip/hip_runtime.h>
#include <hip/hip_bf16.h>

typedef __attribute__((ext_vector_type(8))) short shortx8;
typedef __attribute__((ext_vector_type(4))) float floatx4;

#define B_ 2
#define T_ 2048
#define D_ 1024
#define H_ 16
#define HD_ 64
#define SCALE 0.125f
#define FULLH ((size_t)B_ * H_ * T_ * HD_)   // 4M elems: one [B,H,T,hd] bf16 tensor
#define NEG_BIG -1.0e30f

// float -> bf16 RNE (inputs are sane fp32; no NaN guards needed)
__device__ __forceinline__ short f2bf(float f) {
    union { float f; unsigned u; } v; v.f = f;
    unsigned r = v.u + 0x7FFFu + ((v.u >> 16) & 1u);
    return (short)(r >> 16);
}

// load 8 consecutive floats, convert to 8 bf16
__device__ __forceinline__ shortx8 ldf8_bf(const float* p) {
    const floatx4* q = reinterpret_cast<const floatx4*>(p);
    floatx4 a = q[0], b = q[1];
    shortx8 r;
    r[0] = f2bf(a[0]); r[1] = f2bf(a[1]); r[2] = f2bf(a[2]); r[3] = f2bf(a[3]);
    r[4] = f2bf(b[0]); r[5] = f2bf(b[1]); r[6] = f2bf(b[2]); r[7] = f2bf(b[3]);
    return r;
}

// K/V projection for ALL heads. grid (32, 64): bx -> sel=bx>>4 (0=k,1=v), h=bx&15;
// by -> 64-row m-tile. kv layout: sel*FULLH + ((b*16+h)*T_ + t)*64 + d  (bf16, in d_out)
__global__ __launch_bounds__(256) void kv_gemm(const float* __restrict__ x,
                                               const float* __restrict__ wqkv,
                                               short* __restrict__ kv) {
    __shared__ __align__(16) short As[64][72];
    __shared__ __align__(16) short Bs[64][72];

    const int tid = threadIdx.x;
    const int wv   = tid >> 6;
    const int l    = tid & 63;
    const int ln   = l & 15;
    const int quad = l >> 4;
    const int qd   = quad << 3;
    const int m0   = blockIdx.y * 64;
    const int sel  = blockIdx.x >> 4;
    const int h    = blockIdx.x & 15;
    const int nrow = (sel + 1) * D_ + h * HD_;      // w_qkv row base (k: 1024.., v: 2048..)

    floatx4 acc[4] = {};

    for (int k0 = 0; k0 < D_; k0 += 64) {
        __syncthreads();
        for (int i = tid; i < 512; i += 256) {
            int e = i << 3;
            int r = e >> 6, c = e & 63;
            *reinterpret_cast<shortx8*>(&As[r][c]) = ldf8_bf(&x[(size_t)(m0 + r) * D_ + k0 + c]);
            *reinterpret_cast<shortx8*>(&Bs[r][c]) = ldf8_bf(&wqkv[(size_t)(nrow + r) * D_ + k0 + c]);
        }
        __syncthreads();

        const int mr = (wv << 4) + ln;
#pragma unroll
        for (int kk = 0; kk < 2; ++kk) {
            shortx8 a = *reinterpret_cast<const shortx8*>(&As[mr][kk * 32 + qd]);
#pragma unroll
            for (int nc = 0; nc < 4; ++nc) {
                shortx8 b = *reinterpret_cast<const shortx8*>(&Bs[nc * 16 + ln][kk * 32 + qd]);
                acc[nc] = __builtin_amdgcn_mfma_f32_16x16x32_bf16(a, b, acc[nc], 0, 0, 0);
            }
        }
    }

    short* dst = kv + (size_t)sel * FULLH;
#pragma unroll
    for (int r = 0; r < 4; ++r) {
        int m = m0 + (wv << 4) + (quad << 2) + r;
        int b = m >> 11;
        int t = m & (T_ - 1);
#pragma unroll
        for (int nc = 0; nc < 4; ++nc) {
            int d = nc * 16 + ln;
            dst[((size_t)(b * H_ + h) * T_ + t) * HD_ + d] = f2bf(acc[nc][r]);
        }
    }
}

// Fused q-projection + flash attention (causal + ALiBi), all heads.
// grid 1024: qb=bx&31, h=(bx>>5)&15, b=bx>>9.
// x,wqkv fp32; kv bf16 (in d_out); ao bf16 [B,H,T,hd] (in d_ws).
__global__ __launch_bounds__(256) void attn(const float* __restrict__ x,
                                            const float* __restrict__ wqkv,
                                            const short* __restrict__ kv,
                                            short* __restrict__ ao) {
    __shared__ __align__(16) short Ks[64][72];    // phase 0: x tile
    __shared__ __align__(16) short Vt[64][72];    // phase 0: wq tile; phase 1: Vt[d][kpos]
    __shared__ __align__(16) float Ss[4][16][66]; // phase 0 tail: aliased as Qs (9.2KB < 16.9KB)
    __shared__ __align__(16) short Ps[4][16][72];
    __shared__ float mlds[4][16], llds[4][16], alds[4][16];
    short (*Qs)[72] = reinterpret_cast<short (*)[72]>(&Ss[0][0][0]);

    const int tid = threadIdx.x;
    const int wv   = tid >> 6;
    const int l    = tid & 63;
    const int ln   = l & 15;
    const int quad = l >> 4;
    const int qd   = quad << 3;

    const int qb = blockIdx.x & 31;
    const int h  = (blockIdx.x >> 5) & 15;
    const int b  = blockIdx.x >> 9;

    const float slope = exp2f(-(float)(h + 1) * (1.0f / 16.0f));
    const size_t koff = (size_t)(b * H_ + h) * T_ * HD_;
    const int q0 = qb * 64 + wv * 16;

    // ---- phase 0: q tile = x rows @ (w_qkv q-rows of head h)^T, scale folded in ----
    const float* xrow = x + (size_t)(b * T_ + qb * 64) * D_;
    const float* wq   = wqkv + (size_t)(h * HD_) * D_;

    floatx4 qacc[4] = {};
    for (int k0 = 0; k0 < D_; k0 += 64) {
        __syncthreads();
        for (int i = tid; i < 512; i += 256) {
            int e = i << 3;
            int r = e >> 6, c = e & 63;
            *reinterpret_cast<shortx8*>(&Ks[r][c]) = ldf8_bf(&xrow[(size_t)r * D_ + k0 + c]);
            *reinterpret_cast<shortx8*>(&Vt[r][c]) = ldf8_bf(&wq[(size_t)r * D_ + k0 + c]);
        }
        __syncthreads();

        const int mr = (wv << 4) + ln;
#pragma unroll
        for (int kk = 0; kk < 2; ++kk) {
            shortx8 a = *reinterpret_cast<const shortx8*>(&Ks[mr][kk * 32 + qd]);
#pragma unroll
            for (int nc = 0; nc < 4; ++nc) {
                shortx8 bfr = *reinterpret_cast<const shortx8*>(&Vt[nc * 16 + ln][kk * 32 + qd]);
                qacc[nc] = __builtin_amdgcn_mfma_f32_16x16x32_bf16(a, bfr, qacc[nc], 0, 0, 0);
            }
        }
    }
    // C-layout -> LDS -> A-layout round trip
#pragma unroll
    for (int r = 0; r < 4; ++r)
#pragma unroll
        for (int nc = 0; nc < 4; ++nc)
            Qs[(wv << 4) + (quad << 2) + r][nc * 16 + ln] = f2bf(qacc[nc][r] * SCALE);
    __syncthreads();
    shortx8 qf[2];
#pragma unroll
    for (int kk = 0; kk < 2; ++kk)
        qf[kk] = *reinterpret_cast<const shortx8*>(&Qs[(wv << 4) + ln][kk * 32 + qd]);

    if (l < 16) { mlds[wv][l] = NEG_BIG; llds[wv][l] = 0.0f; }

    // ---- phase 1: flash loop over key blocks ----
    floatx4 oacc[4] = {};

    for (int kb = 0; kb <= qb; ++kb) {
        __syncthreads();
        for (int i = tid; i < 512; i += 256) {
            int e = i << 3;
            int r = e >> 6, c = e & 63;
            *reinterpret_cast<shortx8*>(&Ks[r][c]) =
                *reinterpret_cast<const shortx8*>(&kv[koff + (size_t)(kb * 64 + r) * HD_ + c]);
            shortx8 v = *reinterpret_cast<const shortx8*>(&kv[FULLH + koff + (size_t)(kb * 64 + r) * HD_ + c]);
#pragma unroll
            for (int j = 0; j < 8; ++j) Vt[c + j][r] = v[j];
        }
        __syncthreads();

#pragma unroll
        for (int nc = 0; nc < 4; ++nc) {
            floatx4 s = {};
#pragma unroll
            for (int kk = 0; kk < 2; ++kk) {
                shortx8 bfr = *reinterpret_cast<const shortx8*>(&Ks[nc * 16 + ln][kk * 32 + qd]);
                s = __builtin_amdgcn_mfma_f32_16x16x32_bf16(qf[kk], bfr, s, 0, 0, 0);
            }
#pragma unroll
            for (int r = 0; r < 4; ++r) {
                int row = (quad << 2) + r;
                int q = q0 + row;
                int k = kb * 64 + nc * 16 + ln;
                float raw = s[r] - slope * (float)(q - k);
                Ss[wv][row][nc * 16 + ln] = (k <= q) ? raw : NEG_BIG;
            }
        }
        __syncthreads();

        // online softmax: lanes 0..15 own one query row each
        if (l < 16) {
            int r = l;
            float mold = mlds[wv][r];
            float mx = mold;
#pragma unroll 8
            for (int c = 0; c < 64; ++c) mx = fmaxf(mx, Ss[wv][r][c]);
            float alpha = __expf(mold - mx);
            float sum = 0.0f;
#pragma unroll 8
            for (int c = 0; c < 64; ++c) {
                float p = __expf(Ss[wv][r][c] - mx);
                sum += p;
                Ps[wv][r][c] = f2bf(p);
            }
            mlds[wv][r] = mx;
            llds[wv][r] = llds[wv][r] * alpha + sum;
            alds[wv][r] = alpha;
        }
        __syncthreads();

        // rescale O, then O += P V
#pragma unroll
        for (int r = 0; r < 4; ++r) {
            float a = alds[wv][(quad << 2) + r];
#pragma unroll
            for (int nc = 0; nc < 4; ++nc) oacc[nc][r] *= a;
        }
#pragma unroll
        for (int kk = 0; kk < 2; ++kk) {
            shortx8 pf = *reinterpret_cast<const shortx8*>(&Ps[wv][ln][kk * 32 + qd]);
#pragma unroll
            for (int nc = 0; nc < 4; ++nc) {
                shortx8 bfr = *reinterpret_cast<const shortx8*>(&Vt[nc * 16 + ln][kk * 32 + qd]);
                oacc[nc] = __builtin_amdgcn_mfma_f32_16x16x32_bf16(pf, bfr, oacc[nc], 0, 0, 0);
            }
        }
    }

    // normalize; write head-major bf16
#pragma unroll
    for (int r = 0; r < 4; ++r) {
        int row = (quad << 2) + r;
        float inv = 1.0f / llds[wv][row];
        int t = q0 + row;
#pragma unroll
        for (int nc = 0; nc < 4; ++nc) {
            ao[koff + (size_t)t * HD_ + nc * 16 + ln] = f2bf(oacc[nc][r] * inv);
        }
    }
}

// Final projection: out(fp32) = attn_out(bf16 head-major) @ w_out(fp32)^T
__global__ __launch_bounds__(256) void out_gemm(const short* __restrict__ A,
                                                const float* __restrict__ W,
                                                float* __restrict__ out) {
    __shared__ __align__(16) short As[64][72];
    __shared__ __align__(16) short Bs[64][72];

    const int tid = threadIdx.x;
    const int wv   = tid >> 6;
    const int l    = tid & 63;
    const int ln   = l & 15;
    const int quad = l >> 4;
    const int qd   = quad << 3;
    const int m0   = blockIdx.y * 64;
    const int n0   = blockIdx.x * 64;

    floatx4 acc[4] = {};

    for (int k0 = 0; k0 < D_; k0 += 64) {
        const int h = k0 >> 6;
        __syncthreads();
        for (int i = tid; i < 512; i += 256) {
            int e = i << 3;
            int r = e >> 6, c = e & 63;
            int m = m0 + r;
            int bb = m >> 11, t = m & (T_ - 1);
            size_t aoff = ((size_t)(bb * H_ + h) * T_ + t) * HD_ + c;
            *reinterpret_cast<shortx8*>(&As[r][c]) = *reinterpret_cast<const shortx8*>(A + aoff);
            *reinterpret_cast<shortx8*>(&Bs[r][c]) = ldf8_bf(&W[(size_t)(n0 + r) * D_ + k0 + c]);
        }
        __syncthreads();

        const int mr = (wv << 4) + ln;
#pragma unroll
        for (int kk = 0; kk < 2; ++kk) {
            shortx8 a = *reinterpret_cast<const shortx8*>(&As[mr][kk * 32 + qd]);
#pragma unroll
            for (int nc = 0; nc < 4; ++nc) {
                shortx8 b = *reinterpret_cast<const shortx8*>(&Bs[nc * 16 + ln][kk * 32 + qd]);
                acc[nc] = __builtin_amdgcn_mfma_f32_16x16x32_bf16(a, b, acc[nc], 0, 0, 0);
            }
        }
    }

#pragma unroll
    for (int r = 0; r < 4; ++r) {
        int m = m0 + (wv << 4) + (quad << 2) + r;
#pragma unroll
        for (int nc = 0; nc < 4; ++nc) {
            out[(size_t)m * D_ + n0 + nc * 16 + ln] = acc[nc][r];
        }
    }
}

extern "C" void kernel_launch(void* const* d_in, const int* in_sizes, int n_in,
                              void* d_out, int out_size, void* d_ws, size_t ws_size,
                              hipStream_t stream) {
    const float* x    = (const float*)d_in[0];   // [B,T,D] fp32
    const float* wqkv = (const float*)d_in[1];   // [3D,D]  fp32
    const float* wout = (const float*)d_in[2];   // [D,D]   fp32

    short* kvbuf = (short*)d_out;                // K,V bf16 staging: 2*FULLH = 16MB (== d_out fp32 size)
    short* aws   = (short*)d_ws;                 // attn out bf16 [B,H,T,hd]: 8MB
    float* out   = (float*)d_out;

    // K/V projection: all 16 heads
    kv_gemm<<<dim3(32, 64), 256, 0, stream>>>(x, wqkv, kvbuf);
    // fused q-proj + flash attention
    attn<<<dim3(1024), 256, 0, stream>>>(x, wqkv, kvbuf, aws);
    // final projection (overwrites dead kv staging with fp32 output)
    out_gemm<<<dim3(16, 64), 256, 0, stream>>>(aws, wout, out);
}

// Round 5
// 302.428 us; speedup vs baseline: 2.0007x; 2.0007x over previous
//
#include <hip/hip_runtime.h>
#include <hip/hip_bf16.h>

typedef __attribute__((ext_vector_type(8))) short shortx8;
typedef __attribute__((ext_vector_type(4))) float floatx4;

#define B_ 2
#define T_ 2048
#define D_ 1024
#define H_ 16
#define HD_ 64
#define SCALE 0.125f
#define FULLH ((size_t)B_ * H_ * T_ * HD_)   // 4M elems: one [B,H,T,hd] bf16 tensor
#define NEG_BIG -1.0e30f

// float -> bf16 RNE
__device__ __forceinline__ short f2bf(float f) {
    union { float f; unsigned u; } v; v.f = f;
    unsigned r = v.u + 0x7FFFu + ((v.u >> 16) & 1u);
    return (short)(r >> 16);
}

// load 8 consecutive floats, convert to 8 bf16
__device__ __forceinline__ shortx8 ldf8_bf(const float* p) {
    const floatx4* q = reinterpret_cast<const floatx4*>(p);
    floatx4 a = q[0], b = q[1];
    shortx8 r;
    r[0] = f2bf(a[0]); r[1] = f2bf(a[1]); r[2] = f2bf(a[2]); r[3] = f2bf(a[3]);
    r[4] = f2bf(b[0]); r[5] = f2bf(b[1]); r[6] = f2bf(b[2]); r[7] = f2bf(b[3]);
    return r;
}

// K/V projection. grid (32,64): sel=bx>>4 (0=k,1=v), h=bx&15; by -> 64-row m-tile.
// K stored row-major [b][h][t][d]; V stored TRANSPOSED dim-major [b][h][d][t].
__global__ __launch_bounds__(256) void kv_gemm(const float* __restrict__ x,
                                               const float* __restrict__ wqkv,
                                               short* __restrict__ kv) {
    __shared__ __align__(16) short As[64][72];
    __shared__ __align__(16) short Bs[64][72];

    const int tid = threadIdx.x;
    const int wv   = tid >> 6;
    const int l    = tid & 63;
    const int ln   = l & 15;
    const int quad = l >> 4;
    const int qd   = quad << 3;
    const int m0   = blockIdx.y * 64;
    const int sel  = blockIdx.x >> 4;
    const int h    = blockIdx.x & 15;
    const int nrow = (sel + 1) * D_ + h * HD_;      // w_qkv row base

    floatx4 acc[4] = {};

    for (int k0 = 0; k0 < D_; k0 += 64) {
        __syncthreads();
        for (int i = tid; i < 512; i += 256) {
            int e = i << 3;
            int r = e >> 6, c = e & 63;
            *reinterpret_cast<shortx8*>(&As[r][c]) = ldf8_bf(&x[(size_t)(m0 + r) * D_ + k0 + c]);
            *reinterpret_cast<shortx8*>(&Bs[r][c]) = ldf8_bf(&wqkv[(size_t)(nrow + r) * D_ + k0 + c]);
        }
        __syncthreads();

        const int mr = (wv << 4) + ln;
#pragma unroll
        for (int kk = 0; kk < 2; ++kk) {
            shortx8 a = *reinterpret_cast<const shortx8*>(&As[mr][kk * 32 + qd]);
#pragma unroll
            for (int nc = 0; nc < 4; ++nc) {
                shortx8 b = *reinterpret_cast<const shortx8*>(&Bs[nc * 16 + ln][kk * 32 + qd]);
                acc[nc] = __builtin_amdgcn_mfma_f32_16x16x32_bf16(a, b, acc[nc], 0, 0, 0);
            }
        }
    }

    const int bb = m0 >> 11;
    const int t0 = m0 & (T_ - 1);
    if (sel == 0) {
        // K row-major [b][h][t][d]
#pragma unroll
        for (int r = 0; r < 4; ++r) {
            int t = t0 + (wv << 4) + (quad << 2) + r;
#pragma unroll
            for (int nc = 0; nc < 4; ++nc) {
                kv[((size_t)(bb * H_ + h) * T_ + t) * HD_ + nc * 16 + ln] = f2bf(acc[nc][r]);
            }
        }
    } else {
        // V transposed [b][h][d][t] via LDS bounce (As is dead after last barrier)
        __syncthreads();
#pragma unroll
        for (int r = 0; r < 4; ++r)
#pragma unroll
            for (int nc = 0; nc < 4; ++nc)
                As[nc * 16 + ln][(wv << 4) + (quad << 2) + r] = f2bf(acc[nc][r]);
        __syncthreads();
        const int d = tid >> 2, tseg = (tid & 3) << 4;
        short* vdst = kv + FULLH + ((size_t)(bb * H_ + h) * HD_ + d) * T_ + t0 + tseg;
        *reinterpret_cast<shortx8*>(vdst)     = *reinterpret_cast<const shortx8*>(&As[d][tseg]);
        *reinterpret_cast<shortx8*>(vdst + 8) = *reinterpret_cast<const shortx8*>(&As[d][tseg + 8]);
    }
}

// Fused q-projection + flash attention (causal + ALiBi), all heads.
// grid 1024: qb = 31-(bx&31) (heavy tiles first), h=(bx>>5)&15, b=bx>>9.
__global__ __launch_bounds__(256, 4) void attn(const float* __restrict__ x,
                                               const float* __restrict__ wqkv,
                                               const short* __restrict__ kv,
                                               short* __restrict__ ao) {
    __shared__ __align__(16) short Ks[64][72];   // phase 0: x tile | phase 1: K rows
    __shared__ __align__(16) short Vt[64][72];   // phase 0: wq tile | phase 1: Vt[d][key]
    __shared__ __align__(16) short Ps[4][16][72];// phase 0 tail: aliased as Qs
    short (*Qs)[72] = reinterpret_cast<short (*)[72]>(&Ps[0][0][0]);

    const int tid = threadIdx.x;
    const int wv   = tid >> 6;
    const int l    = tid & 63;
    const int ln   = l & 15;
    const int quad = l >> 4;
    const int qd   = quad << 3;
    const int rowb = quad << 2;                  // C-layout row base within 16-tile

    const int qb = 31 - (blockIdx.x & 31);
    const int h  = (blockIdx.x >> 5) & 15;
    const int b  = blockIdx.x >> 9;

    const float slope = exp2f(-(float)(h + 1) * (1.0f / 16.0f));
    const size_t koff = (size_t)(b * H_ + h) * T_ * HD_;   // also V-transposed head base
    const int q0 = qb * 64 + wv * 16;

    // ---- phase 0: q tile = x rows @ (w_qkv q-rows of head h)^T, scale folded ----
    const float* xrow = x + (size_t)(b * T_ + qb * 64) * D_;
    const float* wq   = wqkv + (size_t)(h * HD_) * D_;

    floatx4 qacc[4] = {};
    for (int k0 = 0; k0 < D_; k0 += 64) {
        __syncthreads();
        for (int i = tid; i < 512; i += 256) {
            int e = i << 3;
            int r = e >> 6, c = e & 63;
            *reinterpret_cast<shortx8*>(&Ks[r][c]) = ldf8_bf(&xrow[(size_t)r * D_ + k0 + c]);
            *reinterpret_cast<shortx8*>(&Vt[r][c]) = ldf8_bf(&wq[(size_t)r * D_ + k0 + c]);
        }
        __syncthreads();

        const int mr = (wv << 4) + ln;
#pragma unroll
        for (int kk = 0; kk < 2; ++kk) {
            shortx8 a = *reinterpret_cast<const shortx8*>(&Ks[mr][kk * 32 + qd]);
#pragma unroll
            for (int nc = 0; nc < 4; ++nc) {
                shortx8 bfr = *reinterpret_cast<const shortx8*>(&Vt[nc * 16 + ln][kk * 32 + qd]);
                qacc[nc] = __builtin_amdgcn_mfma_f32_16x16x32_bf16(a, bfr, qacc[nc], 0, 0, 0);
            }
        }
    }
    // C-layout -> LDS -> A-layout round trip
#pragma unroll
    for (int r = 0; r < 4; ++r)
#pragma unroll
        for (int nc = 0; nc < 4; ++nc)
            Qs[(wv << 4) + rowb + r][nc * 16 + ln] = f2bf(qacc[nc][r] * SCALE);
    __syncthreads();
    shortx8 qf[2];
#pragma unroll
    for (int kk = 0; kk < 2; ++kk)
        qf[kk] = *reinterpret_cast<const shortx8*>(&Qs[(wv << 4) + ln][kk * 32 + qd]);

    // ---- phase 1: flash loop, softmax fully in registers + quad shuffles ----
    float m_run[4], l_run[4];
#pragma unroll
    for (int r = 0; r < 4; ++r) { m_run[r] = NEG_BIG; l_run[r] = 0.0f; }
    floatx4 oacc[4] = {};

    for (int kb = 0; kb <= qb; ++kb) {
        __syncthreads();
        for (int i = tid; i < 512; i += 256) {
            int e = i << 3;
            int r = e >> 6, c = e & 63;
            *reinterpret_cast<shortx8*>(&Ks[r][c]) =
                *reinterpret_cast<const shortx8*>(&kv[koff + ((size_t)(kb * 64 + r) << 6) + c]);
            *reinterpret_cast<shortx8*>(&Vt[r][c]) =
                *reinterpret_cast<const shortx8*>(&kv[FULLH + koff + ((size_t)r << 11) + kb * 64 + c]);
        }
        __syncthreads();

        const bool diag = (kb == qb);
        const int ncmax = diag ? (wv + 1) : 4;

        floatx4 sv[4];
#pragma unroll
        for (int nc = 0; nc < 4; ++nc) {
            if (nc < ncmax) {
                floatx4 s = {};
#pragma unroll
                for (int kk = 0; kk < 2; ++kk) {
                    shortx8 bfr = *reinterpret_cast<const shortx8*>(&Ks[nc * 16 + ln][kk * 32 + qd]);
                    s = __builtin_amdgcn_mfma_f32_16x16x32_bf16(qf[kk], bfr, s, 0, 0, 0);
                }
                sv[nc] = s;
            } else {
                sv[nc] = (floatx4){NEG_BIG, NEG_BIG, NEG_BIG, NEG_BIG};
            }
        }
        // ALiBi as +slope*k (row-constant part cancels in softmax) + causal mask
        const float kbase = slope * (float)(kb * 64 + ln);
#pragma unroll
        for (int nc = 0; nc < 4; ++nc) {
            if (nc < ncmax) {
                float bias = kbase + slope * (float)(nc * 16);
#pragma unroll
                for (int r = 0; r < 4; ++r) {
                    float v = sv[nc][r] + bias;
                    if (diag && nc == wv && ln > rowb + r) v = NEG_BIG;
                    sv[nc][r] = v;
                }
            }
        }
        // row max via quad shuffles; running m/alpha in regs
        float mnew[4], alpha[4], sum[4];
#pragma unroll
        for (int r = 0; r < 4; ++r) {
            float pm = fmaxf(fmaxf(sv[0][r], sv[1][r]), fmaxf(sv[2][r], sv[3][r]));
#pragma unroll
            for (int msk = 1; msk < 16; msk <<= 1)
                pm = fmaxf(pm, __shfl_xor(pm, msk));
            mnew[r] = fmaxf(m_run[r], pm);
            alpha[r] = __expf(m_run[r] - mnew[r]);
            m_run[r] = mnew[r];
            sum[r] = 0.0f;
        }
        // exp (all lanes), pack P to LDS in C-layout
#pragma unroll
        for (int nc = 0; nc < 4; ++nc) {
#pragma unroll
            for (int r = 0; r < 4; ++r) {
                float p = __expf(sv[nc][r] - mnew[r]);
                sum[r] += p;
                Ps[wv][rowb + r][nc * 16 + ln] = f2bf(p);
            }
        }
#pragma unroll
        for (int r = 0; r < 4; ++r) {
#pragma unroll
            for (int msk = 1; msk < 16; msk <<= 1)
                sum[r] += __shfl_xor(sum[r], msk);
            l_run[r] = l_run[r] * alpha[r] + sum[r];
        }
        __syncthreads();

        // rescale O, then O += P V
#pragma unroll
        for (int nc = 0; nc < 4; ++nc)
#pragma unroll
            for (int r = 0; r < 4; ++r) oacc[nc][r] *= alpha[r];
#pragma unroll
        for (int kk = 0; kk < 2; ++kk) {
            if (diag && kk * 32 > wv * 16 + 15) continue;   // P block all-zero
            shortx8 pf = *reinterpret_cast<const shortx8*>(&Ps[wv][ln][kk * 32 + qd]);
#pragma unroll
            for (int nc = 0; nc < 4; ++nc) {
                shortx8 bfr = *reinterpret_cast<const shortx8*>(&Vt[nc * 16 + ln][kk * 32 + qd]);
                oacc[nc] = __builtin_amdgcn_mfma_f32_16x16x32_bf16(pf, bfr, oacc[nc], 0, 0, 0);
            }
        }
    }

    // normalize; write head-major bf16
#pragma unroll
    for (int r = 0; r < 4; ++r) {
        float inv = 1.0f / l_run[r];
        int t = q0 + rowb + r;
#pragma unroll
        for (int nc = 0; nc < 4; ++nc) {
            ao[koff + (size_t)t * HD_ + nc * 16 + ln] = f2bf(oacc[nc][r] * inv);
        }
    }
}

// Final projection: out(fp32) = attn_out(bf16 head-major) @ w_out(fp32)^T
__global__ __launch_bounds__(256) void out_gemm(const short* __restrict__ A,
                                                const float* __restrict__ W,
                                                float* __restrict__ out) {
    __shared__ __align__(16) short As[64][72];
    __shared__ __align__(16) short Bs[64][72];

    const int tid = threadIdx.x;
    const int wv   = tid >> 6;
    const int l    = tid & 63;
    const int ln   = l & 15;
    const int quad = l >> 4;
    const int qd   = quad << 3;
    const int m0   = blockIdx.y * 64;
    const int n0   = blockIdx.x * 64;

    floatx4 acc[4] = {};

    for (int k0 = 0; k0 < D_; k0 += 64) {
        const int h = k0 >> 6;
        __syncthreads();
        for (int i = tid; i < 512; i += 256) {
            int e = i << 3;
            int r = e >> 6, c = e & 63;
            int m = m0 + r;
            int bb = m >> 11, t = m & (T_ - 1);
            size_t aoff = ((size_t)(bb * H_ + h) * T_ + t) * HD_ + c;
            *reinterpret_cast<shortx8*>(&As[r][c]) = *reinterpret_cast<const shortx8*>(A + aoff);
            *reinterpret_cast<shortx8*>(&Bs[r][c]) = ldf8_bf(&W[(size_t)(n0 + r) * D_ + k0 + c]);
        }
        __syncthreads();

        const int mr = (wv << 4) + ln;
#pragma unroll
        for (int kk = 0; kk < 2; ++kk) {
            shortx8 a = *reinterpret_cast<const shortx8*>(&As[mr][kk * 32 + qd]);
#pragma unroll
            for (int nc = 0; nc < 4; ++nc) {
                shortx8 b = *reinterpret_cast<const shortx8*>(&Bs[nc * 16 + ln][kk * 32 + qd]);
                acc[nc] = __builtin_amdgcn_mfma_f32_16x16x32_bf16(a, b, acc[nc], 0, 0, 0);
            }
        }
    }

#pragma unroll
    for (int r = 0; r < 4; ++r) {
        int m = m0 + (wv << 4) + (quad << 2) + r;
#pragma unroll
        for (int nc = 0; nc < 4; ++nc) {
            out[(size_t)m * D_ + n0 + nc * 16 + ln] = acc[nc][r];
        }
    }
}

extern "C" void kernel_launch(void* const* d_in, const int* in_sizes, int n_in,
                              void* d_out, int out_size, void* d_ws, size_t ws_size,
                              hipStream_t stream) {
    const float* x    = (const float*)d_in[0];   // [B,T,D] fp32
    const float* wqkv = (const float*)d_in[1];   // [3D,D]  fp32
    const float* wout = (const float*)d_in[2];   // [D,D]   fp32

    short* kvbuf = (short*)d_out;                // K (row-major) + V (dim-major) bf16: 16MB
    short* aws   = (short*)d_ws;                 // attn out bf16 [B,H,T,hd]: 8MB
    float* out   = (float*)d_out;

    kv_gemm<<<dim3(32, 64), 256, 0, stream>>>(x, wqkv, kvbuf);
    attn<<<dim3(1024), 256, 0, stream>>>(x, wqkv, kvbuf, aws);
    out_gemm<<<dim3(16, 64), 256, 0, stream>>>(aws, wout, out);
}

// Round 6
// 237.681 us; speedup vs baseline: 2.5457x; 1.2724x over previous
//
#include <hip/hip_runtime.h>
#include <hip/hip_bf16.h>

typedef __attribute__((ext_vector_type(8))) short shortx8;
typedef __attribute__((ext_vector_type(4))) float floatx4;
typedef __attribute__((ext_vector_type(4))) unsigned uintx4;
typedef __attribute__((ext_vector_type(2))) unsigned uintx2;

#define B_ 2
#define T_ 2048
#define D_ 1024
#define H_ 16
#define HD_ 64
#define SCALE 0.125f
#define SMAX 16.0f
#define FULLH ((size_t)B_ * H_ * T_ * HD_)   // 4M elems: one [B,H,T,hd] bf16 tensor

// float -> bf16 RNE (scalar, epilogues only)
__device__ __forceinline__ short f2bf(float f) {
    union { float f; unsigned u; } v; v.f = f;
    unsigned r = v.u + 0x7FFFu + ((v.u >> 16) & 1u);
    return (short)(r >> 16);
}

// packed pair fp32 -> bf16x2 (v_cvt_pk_bf16_f32 path)
__device__ __forceinline__ unsigned pk2(float x, float y) {
    union { __hip_bfloat162 h; unsigned u; } t;
    t.h = __float22bfloat162_rn(make_float2(x, y));
    return t.u;
}

// load 8 consecutive floats, convert to 8 bf16 (packed converts)
__device__ __forceinline__ shortx8 ldf8_bf(const float* p) {
    const floatx4* q = reinterpret_cast<const floatx4*>(p);
    floatx4 a = q[0], b = q[1];
    uintx4 r = { pk2(a[0], a[1]), pk2(a[2], a[3]), pk2(b[0], b[1]), pk2(b[2], b[3]) };
    return __builtin_bit_cast(shortx8, r);
}

// Q/K/V projection. grid (48,64): sel=bx>>4 (0=q,1=k,2=v), h=bx&15; by -> 64-row m-tile.
// Q (scaled) and K stored head-major [b][h][t][d]; V stored TRANSPOSED dim-major [b][h][d][t].
__global__ __launch_bounds__(256) void qkv_gemm(const float* __restrict__ x,
                                                const float* __restrict__ wqkv,
                                                short* __restrict__ qout,
                                                short* __restrict__ kv) {
    __shared__ __align__(16) short As[64][72];
    __shared__ __align__(16) short Bs[64][72];

    const int tid = threadIdx.x;
    const int wv   = tid >> 6;
    const int l    = tid & 63;
    const int ln   = l & 15;
    const int quad = l >> 4;
    const int qd   = quad << 3;
    const int m0   = blockIdx.y * 64;
    const int sel  = blockIdx.x >> 4;
    const int h    = blockIdx.x & 15;
    const int nrow = sel * D_ + h * HD_;            // w_qkv row base

    floatx4 acc[4] = {};

    for (int k0 = 0; k0 < D_; k0 += 64) {
        __syncthreads();
        for (int i = tid; i < 512; i += 256) {
            int e = i << 3;
            int r = e >> 6, c = e & 63;
            *reinterpret_cast<shortx8*>(&As[r][c]) = ldf8_bf(&x[(size_t)(m0 + r) * D_ + k0 + c]);
            *reinterpret_cast<shortx8*>(&Bs[r][c]) = ldf8_bf(&wqkv[(size_t)(nrow + r) * D_ + k0 + c]);
        }
        __syncthreads();

        const int mr = (wv << 4) + ln;
#pragma unroll
        for (int kk = 0; kk < 2; ++kk) {
            shortx8 a = *reinterpret_cast<const shortx8*>(&As[mr][kk * 32 + qd]);
#pragma unroll
            for (int nc = 0; nc < 4; ++nc) {
                shortx8 b = *reinterpret_cast<const shortx8*>(&Bs[nc * 16 + ln][kk * 32 + qd]);
                acc[nc] = __builtin_amdgcn_mfma_f32_16x16x32_bf16(a, b, acc[nc], 0, 0, 0);
            }
        }
    }

    const int bb = m0 >> 11;
    const int t0 = m0 & (T_ - 1);
    if (sel < 2) {
        // Q (scaled) or K: head-major [b][h][t][d]
        short* dst = (sel == 0) ? qout : kv;
        const float sc = (sel == 0) ? SCALE : 1.0f;
#pragma unroll
        for (int r = 0; r < 4; ++r) {
            int t = t0 + (wv << 4) + (quad << 2) + r;
#pragma unroll
            for (int nc = 0; nc < 4; ++nc) {
                dst[((size_t)(bb * H_ + h) * T_ + t) * HD_ + nc * 16 + ln] = f2bf(acc[nc][r] * sc);
            }
        }
    } else {
        // V transposed [b][h][d][t] via LDS bounce (As dead after last barrier)
        __syncthreads();
#pragma unroll
        for (int r = 0; r < 4; ++r)
#pragma unroll
            for (int nc = 0; nc < 4; ++nc)
                As[nc * 16 + ln][(wv << 4) + (quad << 2) + r] = f2bf(acc[nc][r]);
        __syncthreads();
        const int d = tid >> 2, tseg = (tid & 3) << 4;
        short* vdst = kv + FULLH + ((size_t)(bb * H_ + h) * HD_ + d) * T_ + t0 + tseg;
        *reinterpret_cast<shortx8*>(vdst)     = *reinterpret_cast<const shortx8*>(&As[d][tseg]);
        *reinterpret_cast<shortx8*>(vdst + 8) = *reinterpret_cast<const shortx8*>(&As[d][tseg + 8]);
    }
}

// Pure flash attention (causal + ALiBi), fixed-max softmax, all heads.
// grid 1024: qb = 31-(bx&31) (heavy first), h=(bx>>5)&15, b=bx>>9.
// Q read from qws (scaled bf16 head-major); output written IN PLACE over own Q tile.
__global__ __launch_bounds__(256, 4) void attn(const short* __restrict__ qws,
                                               const short* __restrict__ kv,
                                               short* ao) {
    __shared__ __align__(16) short Ks[64][72];
    __shared__ __align__(16) short Vt[64][72];      // Vt[d][key]
    __shared__ __align__(16) short Pt[4][64][20];   // per-wave: [key][qrow(16)+pad]

    const int tid = threadIdx.x;
    const int wv   = tid >> 6;
    const int l    = tid & 63;
    const int ln   = l & 15;
    const int quad = l >> 4;
    const int qd   = quad << 3;
    const int rowb = quad << 2;

    const int qb = 31 - (blockIdx.x & 31);
    const int h  = (blockIdx.x >> 5) & 15;
    const int b  = blockIdx.x >> 9;

    const float slope = exp2f(-(float)(h + 1) * (1.0f / 16.0f));
    const size_t koff = (size_t)(b * H_ + h) * T_ * HD_;
    const int q0 = qb * 64 + wv * 16;

    // Q fragments (A-layout) directly from global
    shortx8 qf[2];
#pragma unroll
    for (int kk = 0; kk < 2; ++kk)
        qf[kk] = *reinterpret_cast<const shortx8*>(&qws[koff + (size_t)(q0 + ln) * HD_ + kk * 32 + qd]);

    // staging geometry: thread covers (r0,c0) and (r0+32,c0), 8 shorts each
    const int r0 = tid >> 3, c0 = (tid & 7) << 3, r1 = r0 + 32;
    const short* kbase = kv + koff;
    const short* vbase = kv + FULLH + koff;
    shortx8 kA, kB, vA, vB;
    auto FETCH = [&](int kb) {
        const short* kp = kbase + ((size_t)(kb * 64) << 6);
        kA = *reinterpret_cast<const shortx8*>(kp + ((size_t)r0 << 6) + c0);
        kB = *reinterpret_cast<const shortx8*>(kp + ((size_t)r1 << 6) + c0);
        const short* vp = vbase + kb * 64;
        vA = *reinterpret_cast<const shortx8*>(vp + ((size_t)r0 << 11) + c0);
        vB = *reinterpret_cast<const shortx8*>(vp + ((size_t)r1 << 11) + c0);
    };

    floatx4 oacc[4] = {};
    floatx4 lsum = {};
    const shortx8 ones = {16256, 16256, 16256, 16256, 16256, 16256, 16256, 16256}; // bf16 1.0
    const float base0 = -SMAX - slope * (float)(q0 + rowb);

    FETCH(0);
    for (int kb = 0; kb <= qb; ++kb) {
        __syncthreads();                              // prior readers of Ks/Vt done
        *reinterpret_cast<shortx8*>(&Ks[r0][c0]) = kA;
        *reinterpret_cast<shortx8*>(&Ks[r1][c0]) = kB;
        *reinterpret_cast<shortx8*>(&Vt[r0][c0]) = vA;
        *reinterpret_cast<shortx8*>(&Vt[r1][c0]) = vB;
        __syncthreads();                              // tiles visible
        if (kb < qb) FETCH(kb + 1);                   // prefetch: latency hidden by compute below

        const bool diag = (kb == qb);
        const int ncmax = diag ? (wv + 1) : 4;
        const int kln = kb * 64 + ln;
        const float bb0 = slope * (float)kln + base0; // slope*(k-q) - SMAX, per-row offset below

        // S tiles -> p = exp(s + bias - SMAX), packed to Pt (transposed, b64 writes)
#pragma unroll
        for (int nc = 0; nc < 4; ++nc) {
            floatx4 s = {};
            if (nc < ncmax) {
#pragma unroll
                for (int kk = 0; kk < 2; ++kk) {
                    shortx8 bfr = *reinterpret_cast<const shortx8*>(&Ks[nc * 16 + ln][kk * 32 + qd]);
                    s = __builtin_amdgcn_mfma_f32_16x16x32_bf16(qf[kk], bfr, s, 0, 0, 0);
                }
            }
            float p[4];
#pragma unroll
            for (int r = 0; r < 4; ++r) {
                bool ok = (kln + nc * 16) <= (q0 + rowb + r);
                float e = __expf(s[r] + bb0 + slope * (float)(nc * 16 - r));
                p[r] = ok ? e : 0.0f;
            }
            uintx2 pkd = { pk2(p[0], p[1]), pk2(p[2], p[3]) };
            *reinterpret_cast<uintx2*>(&Pt[wv][nc * 16 + ln][rowb]) = pkd;
        }

        // O += P V ; l += P 1  (Pt is wave-private: no barrier)
#pragma unroll
        for (int kk = 0; kk < 2; ++kk) {
            if (diag && kk * 32 > wv * 16 + 15) continue;   // all-zero P block
            shortx8 pf;
#pragma unroll
            for (int j = 0; j < 8; ++j) pf[j] = Pt[wv][kk * 32 + qd + j][ln];
            lsum = __builtin_amdgcn_mfma_f32_16x16x32_bf16(pf, ones, lsum, 0, 0, 0);
#pragma unroll
            for (int nc = 0; nc < 4; ++nc) {
                shortx8 bfr = *reinterpret_cast<const shortx8*>(&Vt[nc * 16 + ln][kk * 32 + qd]);
                oacc[nc] = __builtin_amdgcn_mfma_f32_16x16x32_bf16(pf, bfr, oacc[nc], 0, 0, 0);
            }
        }
    }

    // normalize; write head-major bf16 over own Q tile
#pragma unroll
    for (int r = 0; r < 4; ++r) {
        float inv = 1.0f / lsum[r];
        int t = q0 + rowb + r;
#pragma unroll
        for (int nc = 0; nc < 4; ++nc) {
            ao[koff + (size_t)t * HD_ + nc * 16 + ln] = f2bf(oacc[nc][r] * inv);
        }
    }
}

// Final projection: out(fp32) = attn_out(bf16 head-major) @ w_out(fp32)^T
__global__ __launch_bounds__(256) void out_gemm(const short* __restrict__ A,
                                                const float* __restrict__ W,
                                                float* __restrict__ out) {
    __shared__ __align__(16) short As[64][72];
    __shared__ __align__(16) short Bs[64][72];

    const int tid = threadIdx.x;
    const int wv   = tid >> 6;
    const int l    = tid & 63;
    const int ln   = l & 15;
    const int quad = l >> 4;
    const int qd   = quad << 3;
    const int m0   = blockIdx.y * 64;
    const int n0   = blockIdx.x * 64;

    floatx4 acc[4] = {};

    for (int k0 = 0; k0 < D_; k0 += 64) {
        const int h = k0 >> 6;
        __syncthreads();
        for (int i = tid; i < 512; i += 256) {
            int e = i << 3;
            int r = e >> 6, c = e & 63;
            int m = m0 + r;
            int bb = m >> 11, t = m & (T_ - 1);
            size_t aoff = ((size_t)(bb * H_ + h) * T_ + t) * HD_ + c;
            *reinterpret_cast<shortx8*>(&As[r][c]) = *reinterpret_cast<const shortx8*>(A + aoff);
            *reinterpret_cast<shortx8*>(&Bs[r][c]) = ldf8_bf(&W[(size_t)(n0 + r) * D_ + k0 + c]);
        }
        __syncthreads();

        const int mr = (wv << 4) + ln;
#pragma unroll
        for (int kk = 0; kk < 2; ++kk) {
            shortx8 a = *reinterpret_cast<const shortx8*>(&As[mr][kk * 32 + qd]);
#pragma unroll
            for (int nc = 0; nc < 4; ++nc) {
                shortx8 b = *reinterpret_cast<const shortx8*>(&Bs[nc * 16 + ln][kk * 32 + qd]);
                acc[nc] = __builtin_amdgcn_mfma_f32_16x16x32_bf16(a, b, acc[nc], 0, 0, 0);
            }
        }
    }

#pragma unroll
    for (int r = 0; r < 4; ++r) {
        int m = m0 + (wv << 4) + (quad << 2) + r;
#pragma unroll
        for (int nc = 0; nc < 4; ++nc) {
            out[(size_t)m * D_ + n0 + nc * 16 + ln] = acc[nc][r];
        }
    }
}

extern "C" void kernel_launch(void* const* d_in, const int* in_sizes, int n_in,
                              void* d_out, int out_size, void* d_ws, size_t ws_size,
                              hipStream_t stream) {
    const float* x    = (const float*)d_in[0];   // [B,T,D] fp32
    const float* wqkv = (const float*)d_in[1];   // [3D,D]  fp32
    const float* wout = (const float*)d_in[2];   // [D,D]   fp32

    short* kvbuf = (short*)d_out;                // K (head-major) + V (dim-major) bf16: 16MB
    short* qws   = (short*)d_ws;                 // Q scaled bf16 head-major; attn out in-place: 8MB
    float* out   = (float*)d_out;

    qkv_gemm<<<dim3(48, 64), 256, 0, stream>>>(x, wqkv, qws, kvbuf);
    attn<<<dim3(1024), 256, 0, stream>>>(qws, kvbuf, qws);
    out_gemm<<<dim3(16, 64), 256, 0, stream>>>(qws, wout, out);
}